// Round 3
// baseline (277.201 us; speedup 1.0000x reference)
//
#include <hip/hip_runtime.h>
#include <hip/hip_bf16.h>
#include <stdint.h>

// B=4, N=2048, C=1024, H=16, HD=64; 8192 token rows.
typedef __bf16 bf16_t;
typedef __attribute__((ext_vector_type(8))) __bf16 bf16x8;
typedef __attribute__((ext_vector_type(4))) __bf16 bf16x4;
typedef __attribute__((ext_vector_type(4))) float floatx4;
typedef __attribute__((ext_vector_type(4))) _Float16 half4_t;

#define GLDS16(g, l)                                                          \
  __builtin_amdgcn_global_load_lds(                                           \
      (const __attribute__((address_space(1))) void*)(g),                     \
      (__attribute__((address_space(3))) void*)(l), 16, 0, 0)

// ---------------------------------------------------------------------------
// Legacy 128x128 / 64x64 tile GEMM (m97 structure). Used for the small
// W_comb GEMM and GEMM2 (N=1024: a 256^2 grid would idle half the CUs).
// ---------------------------------------------------------------------------
template <int IT, int JT, typename OT>
__global__ __launch_bounds__(256) void gemm_bt(
    const bf16_t* __restrict__ A, const bf16_t* __restrict__ B,
    const float* __restrict__ bias, OT* __restrict__ C, int M, int N, int K) {
  constexpr int AROWS = 32 * IT;
  constexpr int BROWS = 32 * JT;
  constexpr int COLS = BROWS;
  constexpr int STAGE = (AROWS + BROWS) * 64;
  constexpr int EPI = (sizeof(OT) == 2) ? AROWS * COLS : 0;
  constexpr int SME = STAGE > EPI ? STAGE : EPI;
  __shared__ bf16_t sm[SME];
  bf16_t* As = sm;
  bf16_t* Bs = sm + AROWS * 64;

  const int tid = threadIdx.x;
  const int wave = tid >> 6;
  const int lane = tid & 63;
  const int quad = lane >> 4;
  const int l16 = lane & 15;
  const int m0 = blockIdx.x * AROWS;
  const int n0 = blockIdx.y * BROWS;
  const int wm = (wave >> 1) * (IT * 16);
  const int wn = (wave & 1) * (JT * 16);

  const int ra = wave * (8 * IT) + (lane >> 3);
  const int ga = ((lane & 7) ^ (ra & 7)) * 8;
  const int rb = wave * (8 * JT) + (lane >> 3);
  const int gb = ((lane & 7) ^ (rb & 7)) * 8;
  const bf16_t* Ab = A + (size_t)(m0 + ra) * K + ga;
  const bf16_t* Bb = B + (size_t)(n0 + rb) * K + gb;
  const int p0 = (quad ^ (l16 & 7)) * 8;

  floatx4 acc[IT][JT];
  const floatx4 zf = {0.f, 0.f, 0.f, 0.f};
#pragma unroll
  for (int i = 0; i < IT; ++i)
#pragma unroll
    for (int j = 0; j < JT; ++j) acc[i][j] = zf;

  for (int k0 = 0; k0 < K; k0 += 64) {
#pragma unroll
    for (int t = 0; t < IT; ++t)
      GLDS16(Ab + (size_t)(t * 8) * K + k0, As + (wave * (64 * IT) + t * 64) * 8);
#pragma unroll
    for (int t = 0; t < JT; ++t)
      GLDS16(Bb + (size_t)(t * 8) * K + k0, Bs + (wave * (64 * JT) + t * 64) * 8);
    __syncthreads();
#pragma unroll
    for (int ks = 0; ks < 2; ++ks) {
      const int ko = p0 ^ (ks * 32);
      bf16x8 af[IT], bfr[JT];
#pragma unroll
      for (int i = 0; i < IT; ++i)
        af[i] = *(const bf16x8*)(As + (wm + i * 16 + l16) * 64 + ko);
#pragma unroll
      for (int j = 0; j < JT; ++j)
        bfr[j] = *(const bf16x8*)(Bs + (wn + j * 16 + l16) * 64 + ko);
#pragma unroll
      for (int i = 0; i < IT; ++i)
#pragma unroll
        for (int j = 0; j < JT; ++j)
          acc[i][j] = __builtin_amdgcn_mfma_f32_16x16x32_bf16(
              bfr[j], af[i], acc[i][j], 0, 0, 0);
    }
    __syncthreads();
  }

  if constexpr (sizeof(OT) == 4) {
#pragma unroll
    for (int j = 0; j < JT; ++j) {
      const int colb = n0 + wn + j * 16 + quad * 4;
      floatx4 bv = zf;
      if (bias) bv = *(const floatx4*)(bias + colb);
#pragma unroll
      for (int i = 0; i < IT; ++i) {
        const int row = m0 + wm + i * 16 + l16;
        floatx4 v = acc[i][j] + bv;
        *(floatx4*)((float*)C + (size_t)row * N + colb) = v;
      }
    }
  } else {
    constexpr int SWZ = COLS / 32;
    constexpr int CPR = COLS / 8;
    constexpr int PASSES = (AROWS * CPR) / 256;
#pragma unroll
    for (int j = 0; j < JT; ++j) {
      const int colb = n0 + wn + j * 16 + quad * 4;
      floatx4 bv = zf;
      if (bias) bv = *(const floatx4*)(bias + colb);
      const int gcol = (wn + j * 16 + quad * 4) >> 2;
#pragma unroll
      for (int i = 0; i < IT; ++i) {
        const int rl = wm + i * 16 + l16;
        floatx4 v = acc[i][j] + bv;
        union {
          bf16_t b[4];
          uint2 u2;
        } pk;
        pk.b[0] = (bf16_t)v[0];
        pk.b[1] = (bf16_t)v[1];
        pk.b[2] = (bf16_t)v[2];
        pk.b[3] = (bf16_t)v[3];
        const int gsw = gcol ^ ((rl & 7) * SWZ);
        *(uint2*)(sm + rl * COLS + gsw * 4) = pk.u2;
      }
    }
    __syncthreads();
    bf16_t* Cb = (bf16_t*)C;
#pragma unroll
    for (int pass = 0; pass < PASSES; ++pass) {
      const int f = pass * 256 + tid;
      const int row = f / CPR;
      const int c16 = f % CPR;
      const int g0 = (2 * c16) ^ ((row & 7) * SWZ);
      uint4 v = *(const uint4*)(sm + row * COLS + g0 * 4);
      *(uint4*)(Cb + (size_t)(m0 + row) * N + n0 + c16 * 8) = v;
    }
  }
}

// ---------------------------------------------------------------------------
// 256x256 counted-vmcnt GEMM, merged-region variant.
// Round-1 post-mortem: the 8-phase lockstep [LD|BAR|MFMA|BAR] serialized the
// LDS drain (~375-560cy) against the MFMA burst (~620cy) -> MfmaUtil 39%.
// Fix: ONE compute region per K-tile {24 ds_read + 64 MFMA, compiler
// fine-grained lgkmcnt interleave}, then BAR; stage tile t+2 into the
// just-read buffer; VMCNT(8) (= tile t+1 landed, t+2 in flight -- never
// drain to 0); BAR. Barriers 8->2 per tile. Hazard-free: a wave's last MFMA
// cannot issue until its reads completed (lgkmcnt), so at the barrier the
// read queue for this buffer is empty before the overwrite is staged; the
// GLDS write additionally lands ~500cy after issue.
// LDS 128 KiB: [A|B][2buf][2khalf][256 rows][32 elems], st_16x32 swizzle
// realized by pre-swizzled GLOBAL source column (LDS dest linear, m173).
// No XCD swizzle: inputs (24 MB) are L3-resident; linear block order keeps
// G1out writes in mid_k's read order.
// ---------------------------------------------------------------------------
#define BAR8 asm volatile("s_barrier" ::: "memory")
#define VMCNT(n) asm volatile("s_waitcnt vmcnt(" #n ")" ::: "memory")

__global__ __launch_bounds__(512, 2) void gemm8p(
    const bf16_t* __restrict__ A, const bf16_t* __restrict__ B,
    const float* __restrict__ bias, bf16_t* __restrict__ C, int M, int N,
    int K) {
  __shared__ bf16_t sm8[65536];  // 128 KiB; reused as 256x256 C-stage.
  bf16_t* As = sm8;              // [buf][kh][row 256][32] elems
  bf16_t* Bs = sm8 + 32768;

  const int tid = threadIdx.x;
  const int wave = tid >> 6, lane = tid & 63;
  const int l16 = lane & 15, quad = lane >> 4;
  const int wm = (wave >> 2) * 128, wn = (wave & 3) * 64;

  const int m0 = blockIdx.y << 8, n0 = blockIdx.x << 8;

  // Staging: wave w covers LDS rows w*32..w*32+31 of a half-tile (2 GLDS16).
  // Global column pre-swizzled so the linear GLDS write realizes the
  // bit9->bit5 LDS XOR swizzle (st_16x32).
  const int srow = wave * 32 + (lane >> 2);
  const int kswz = ((lane & 3) * 8) ^ ((lane >> 5) << 4);
  const bf16_t* Ag = A + (size_t)(m0 + srow) * K + kswz;
  const bf16_t* Bg = B + (size_t)(n0 + srow) * K + kswz;
  const int sdst = wave * 1024;        // elem offset of wave's chunk (q=0)
  const size_t a16k = (size_t)K << 4;  // 16 global rows

  // Fragment read offset: swizzled k-group (read-side of st_16x32).
  const int koe = (quad * 8) ^ ((l16 & 8) << 1);
  const int aoff = (wm + l16) * 32 + koe;
  const int boff = (wn + l16) * 32 + koe;

  floatx4 acc[8][4];
  const floatx4 zf = {0.f, 0.f, 0.f, 0.f};
#pragma unroll
  for (int i = 0; i < 8; ++i)
#pragma unroll
    for (int j = 0; j < 4; ++j) acc[i][j] = zf;

#define STG_A(buf, kh)                                           \
  do {                                                           \
    bf16_t* _d = As + (buf)*16384 + (kh)*8192 + sdst;            \
    GLDS16(Ag + (kh)*32, _d);                                    \
    GLDS16(Ag + a16k + (kh)*32, _d + 512);                       \
  } while (0)
#define STG_B(buf, kh)                                           \
  do {                                                           \
    bf16_t* _d = Bs + (buf)*16384 + (kh)*8192 + sdst;            \
    GLDS16(Bg + (kh)*32, _d);                                    \
    GLDS16(Bg + a16k + (kh)*32, _d + 512);                       \
  } while (0)
#define STG4(buf)                                                \
  do {                                                           \
    STG_A(buf, 0);                                               \
    STG_A(buf, 1);                                               \
    STG_B(buf, 0);                                               \
    STG_B(buf, 1);                                               \
    Ag += 64;                                                    \
    Bg += 64;                                                    \
  } while (0)

// One K-half: 12 ds_read_b128 up-front, then 32 MFMA. No barriers inside --
// the compiler emits counted lgkmcnt so MFMAs start as operands land and the
// LDS drain hides under the MFMA stream (cross-wave and intra-wave overlap).
#define KHALF(buf, kh)                                                    \
  do {                                                                    \
    const bf16_t* _pb = Bs + (buf)*16384 + (kh)*8192 + boff;              \
    const bf16_t* _pa = As + (buf)*16384 + (kh)*8192 + aoff;              \
    bf16x8 bfr0 = *(const bf16x8*)(_pb);                                  \
    bf16x8 bfr1 = *(const bf16x8*)(_pb + 512);                            \
    bf16x8 bfr2 = *(const bf16x8*)(_pb + 1024);                           \
    bf16x8 bfr3 = *(const bf16x8*)(_pb + 1536);                           \
    bf16x8 afa[4], afb[4];                                                \
    _Pragma("unroll") for (int _i = 0; _i < 4; ++_i)                      \
        afa[_i] = *(const bf16x8*)(_pa + _i * 512);                       \
    _Pragma("unroll") for (int _i = 0; _i < 4; ++_i)                      \
        afb[_i] = *(const bf16x8*)(_pa + 2048 + _i * 512);                \
    __builtin_amdgcn_s_setprio(1);                                        \
    _Pragma("unroll") for (int _i = 0; _i < 4; ++_i) {                    \
      acc[_i][0] = __builtin_amdgcn_mfma_f32_16x16x32_bf16(               \
          bfr0, afa[_i], acc[_i][0], 0, 0, 0);                            \
      acc[_i][1] = __builtin_amdgcn_mfma_f32_16x16x32_bf16(               \
          bfr1, afa[_i], acc[_i][1], 0, 0, 0);                            \
      acc[_i][2] = __builtin_amdgcn_mfma_f32_16x16x32_bf16(               \
          bfr2, afa[_i], acc[_i][2], 0, 0, 0);                            \
      acc[_i][3] = __builtin_amdgcn_mfma_f32_16x16x32_bf16(               \
          bfr3, afa[_i], acc[_i][3], 0, 0, 0);                            \
    }                                                                     \
    _Pragma("unroll") for (int _i = 0; _i < 4; ++_i) {                    \
      acc[4 + _i][0] = __builtin_amdgcn_mfma_f32_16x16x32_bf16(           \
          bfr0, afb[_i], acc[4 + _i][0], 0, 0, 0);                        \
      acc[4 + _i][1] = __builtin_amdgcn_mfma_f32_16x16x32_bf16(           \
          bfr1, afb[_i], acc[4 + _i][1], 0, 0, 0);                        \
      acc[4 + _i][2] = __builtin_amdgcn_mfma_f32_16x16x32_bf16(           \
          bfr2, afb[_i], acc[4 + _i][2], 0, 0, 0);                        \
      acc[4 + _i][3] = __builtin_amdgcn_mfma_f32_16x16x32_bf16(           \
          bfr3, afb[_i], acc[4 + _i][3], 0, 0, 0);                        \
    }                                                                     \
    __builtin_amdgcn_s_setprio(0);                                        \
  } while (0)

  // Prologue: stage tiles 0 (buf0) and 1 (buf1); wait tile0 landed (8 of 16).
  STG_A(0, 0);
  STG_A(0, 1);
  STG_B(0, 0);
  STG_B(0, 1);
  Ag += 64;
  Bg += 64;
  STG_A(1, 0);
  STG_A(1, 1);
  STG_B(1, 0);
  STG_B(1, 1);
  Ag += 64;
  Bg += 64;
  VMCNT(8);
  BAR8;

  const int NT = K >> 6;  // K-tiles (NT even, >= 4)
  for (int it = 0; it < NT / 2 - 1; ++it) {
    KHALF(0, 0);
    KHALF(0, 1);
    BAR8;
    STG4(0);  // tile 2it+2 -> buf0 (just fully read)
    VMCNT(8);
    BAR8;
    KHALF(1, 0);
    KHALF(1, 1);
    BAR8;
    STG4(1);  // tile 2it+3 -> buf1
    VMCNT(8);
    BAR8;
  }
  // Tail: tiles NT-2 (buf0) and NT-1 (buf1); no more staging.
  KHALF(0, 0);
  KHALF(0, 1);
  BAR8;
  VMCNT(0);
  BAR8;
  KHALF(1, 0);
  KHALF(1, 1);
  __syncthreads();

  // ---- bf16 epilogue: acc -> LDS (XOR-swizzled 8B granules) -> 16B stores.
  const int crow_b = wm + l16;
#pragma unroll
  for (int nj = 0; nj < 4; ++nj) {
    const int colb = wn + nj * 16 + quad * 4;
    floatx4 bv = zf;
    if (bias) bv = *(const floatx4*)(bias + n0 + colb);
#pragma unroll
    for (int mi = 0; mi < 8; ++mi) {
      const int row = crow_b + mi * 16;
      floatx4 v = acc[mi][nj] + bv;
      union {
        bf16_t b[4];
        uint2 u2;
      } pk;
      pk.b[0] = (bf16_t)v[0];
      pk.b[1] = (bf16_t)v[1];
      pk.b[2] = (bf16_t)v[2];
      pk.b[3] = (bf16_t)v[3];
      const int cb = (colb * 2) ^ ((row & 31) << 4);
      *(uint2*)((char*)sm8 + row * 512 + cb) = pk.u2;
    }
  }
  __syncthreads();
#pragma unroll
  for (int pass = 0; pass < 16; ++pass) {
    const int flat = pass * 8192 + tid * 16;
    const int row = flat >> 9;
    const int cb = flat & 511;
    const int cbs = cb ^ ((row & 31) << 4);
    uint4 v = *(const uint4*)((char*)sm8 + row * 512 + cbs);
    *(uint4*)((char*)C + ((size_t)(m0 + row) * N + n0) * 2 + cb) = v;
  }
#undef STG_A
#undef STG_B
#undef STG4
#undef KHALF
}

// ---------------------------------------------------------------------------
// prep2: all fp32->bf16 converts, bias assembly, Wcp transpose, bcomb.
// ---------------------------------------------------------------------------
__global__ __launch_bounds__(256) void prep2_k(
    const float* __restrict__ x, bf16_t* __restrict__ x_bf,
    const float* __restrict__ Wqkv, bf16_t* __restrict__ Wbig1,
    const float* __restrict__ Wpw, bf16_t* __restrict__ Wpw_bf,
    const float* __restrict__ Wout, const float* __restrict__ Wtw,
    bf16_t* __restrict__ Wbig2, const float* __restrict__ bqkv,
    float* __restrict__ bias1, const float* __restrict__ bout,
    const float* __restrict__ btw, float* __restrict__ bias2,
    const float* __restrict__ Wcp, bf16_t* __restrict__ WcpT,
    const float* __restrict__ bcp, const float* __restrict__ bpw) {
  __shared__ float t[32][33];
  const int b = blockIdx.x, tid = threadIdx.x;
  auto cvt4 = [](const float* in, bf16_t* out, int i) {
    floatx4 v = ((const floatx4*)in)[i];
    bf16x4 o;
    o[0] = (bf16_t)v[0];
    o[1] = (bf16_t)v[1];
    o[2] = (bf16_t)v[2];
    o[3] = (bf16_t)v[3];
    ((bf16x4*)out)[i] = o;
  };
  if (b < 8192) {
    cvt4(x, x_bf, b * 256 + tid);
  } else if (b < 11264) {
    cvt4(Wqkv, Wbig1, (b - 8192) * 256 + tid);
  } else if (b < 12288) {
    cvt4(Wpw, Wpw_bf, (b - 11264) * 256 + tid);
  } else if (b < 14336) {
    const bool second = b >= 13312;
    int i = (b - (second ? 13312 : 12288)) * 256 + tid;
    floatx4 v = ((const floatx4*)(second ? Wtw : Wout))[i];
    bf16x4 o;
    o[0] = (bf16_t)v[0];
    o[1] = (bf16_t)v[1];
    o[2] = (bf16_t)v[2];
    o[3] = (bf16_t)v[3];
    int row = i >> 8, c4 = i & 255;
    *(bf16x4*)(Wbig2 + (size_t)row * 2048 + (second ? 1024 : 0) + c4 * 4) = o;
  } else if (b < 14339) {
    int i = (b - 14336) * 256 + tid;
    if (i < 768) ((floatx4*)bias1)[i] = ((const floatx4*)bqkv)[i];
  } else if (b == 14339) {
    ((floatx4*)bias2)[tid] =
        ((const floatx4*)bout)[tid] + ((const floatx4*)btw)[tid];
  } else if (b < 15364) {
    const int tb = b - 14340;
    const int bx = (tb & 31) * 32, by = (tb >> 5) * 32;
    const int tx = tid & 31, ty = tid >> 5;
#pragma unroll
    for (int iq = 0; iq < 4; ++iq)
      t[ty + iq * 8][tx] = Wcp[(size_t)(by + ty + iq * 8) * 1024 + bx + tx];
    __syncthreads();
#pragma unroll
    for (int iq = 0; iq < 4; ++iq)
      WcpT[(size_t)(bx + ty + iq * 8) * 1024 + by + tx] =
          (bf16_t)t[tx][ty + iq * 8];
  } else {
    const int row = (b - 15364) * 4 + (tid >> 6);
    const int l = tid & 63;
    const float* wr = Wpw + (size_t)row * 1024;
    float s = 0.f;
    for (int j = l; j < 1024; j += 64) s += wr[j] * bcp[j];
#pragma unroll
    for (int o = 32; o > 0; o >>= 1) s += __shfl_down(s, o);
    if (l == 0) bias1[3072 + row] = s + bpw[row];
  }
}

static __device__ inline void exp8(uint32_t w0, uint32_t w1, uint32_t w2,
                                   uint32_t w3, float* f) {
  f[0] = __uint_as_float(w0 << 16);
  f[1] = __uint_as_float(w0 & 0xffff0000u);
  f[2] = __uint_as_float(w1 << 16);
  f[3] = __uint_as_float(w1 & 0xffff0000u);
  f[4] = __uint_as_float(w2 << 16);
  f[5] = __uint_as_float(w2 & 0xffff0000u);
  f[6] = __uint_as_float(w3 << 16);
  f[7] = __uint_as_float(w3 & 0xffff0000u);
}

// ---------------------------------------------------------------------------
// mid: blocks [0,2048) = MFMA attention (one wave/token);
//      blocks [2048,3072) = depthwise conv k=3.
// ---------------------------------------------------------------------------
__global__ __launch_bounds__(256) void mid_k(const bf16_t* __restrict__ G1,
                                             const float* __restrict__ pos,
                                             const float* __restrict__ Wdw,
                                             const float* __restrict__ bdw,
                                             bf16_t* __restrict__ Mid) {
  __shared__ bf16_t ost[4][16 * 68];
  const int tid = threadIdx.x;
  if (blockIdx.x < 2048) {
    const int wave = tid >> 6, lane = tid & 63;
    const int p = blockIdx.x * 4 + wave;
    const int l16 = lane & 15, quad = lane >> 4;
    const bf16_t* row = G1 + (size_t)p * 4096;
    const bf16_t* qb = row + l16 * 192 + quad * 8;

    bf16x8 q0 = *(const bf16x8*)(qb);
    bf16x8 q1 = *(const bf16x8*)(qb + 32);
    bf16x8 k0 = *(const bf16x8*)(qb + 64);
    bf16x8 k1 = *(const bf16x8*)(qb + 96);
    floatx4 S = {0.f, 0.f, 0.f, 0.f};
    S = __builtin_amdgcn_mfma_f32_16x16x32_bf16(k0, q0, S, 0, 0, 0);
    S = __builtin_amdgcn_mfma_f32_16x16x32_bf16(k1, q1, S, 0, 0, 0);

    const floatx4 pb = *(const floatx4*)(pos + (size_t)(p & 2047) * 256 +
                                         l16 * 16 + quad * 4);
    float v[4];
#pragma unroll
    for (int r = 0; r < 4; ++r) v[r] = S[r] * 0.125f + pb[r];

    float m = fmaxf(fmaxf(v[0], v[1]), fmaxf(v[2], v[3]));
    m = fmaxf(m, __shfl_xor(m, 16));
    m = fmaxf(m, __shfl_xor(m, 32));
    float e[4], sum = 0.f;
#pragma unroll
    for (int r = 0; r < 4; ++r) {
      e[r] = __expf(v[r] - m);
      sum += e[r];
    }
    sum += __shfl_xor(sum, 16);
    sum += __shfl_xor(sum, 32);
    const float inv = 1.0f / sum;
    half4_t pa;
#pragma unroll
    for (int r = 0; r < 4; ++r) pa[r] = (_Float16)(e[r] * inv);

    const bf16_t* vb_base = row + 128 + l16;
    const floatx4 zf = {0.f, 0.f, 0.f, 0.f};
    floatx4 o[4];
#pragma unroll
    for (int t = 0; t < 4; ++t) {
      half4_t vb;
#pragma unroll
      for (int j = 0; j < 4; ++j)
        vb[j] = (_Float16)(float)vb_base[(quad * 4 + j) * 192 + t * 16];
      o[t] = __builtin_amdgcn_mfma_f32_16x16x16f16(pa, vb, zf, 0, 0, 0);
    }

    bf16_t* ow = ost[wave];
#pragma unroll
    for (int r = 0; r < 4; ++r)
#pragma unroll
      for (int t = 0; t < 4; ++t)
        ow[(quad * 4 + r) * 68 + t * 16 + l16] = (bf16_t)o[t][r];
    const int h2 = lane >> 2, m4 = lane & 3;
    const bf16_t* srcp = ow + h2 * 68 + m4 * 16;
    uint2 a0 = *(const uint2*)(srcp);
    uint2 a1 = *(const uint2*)(srcp + 4);
    uint2 a2 = *(const uint2*)(srcp + 8);
    uint2 a3 = *(const uint2*)(srcp + 12);
    uint4 s0 = {a0.x, a0.y, a1.x, a1.y};
    uint4 s1 = {a2.x, a2.y, a3.x, a3.y};
    uint4* dst = (uint4*)(Mid + (size_t)p * 2048 + h2 * 64 + m4 * 16);
    dst[0] = s0;
    dst[1] = s1;
  } else {
    const bf16_t* in = G1 + 3072;
    bf16_t* out = Mid + 1024;
    const int item = (blockIdx.x - 2048) * 256 + tid;
    const int cc = item & 127, rowg = item >> 7;
    const int c0 = cc * 8;
    float w0[8], w1[8], w2[8], bb[8];
#pragma unroll
    for (int c = 0; c < 8; ++c) {
      w0[c] = Wdw[(c0 + c) * 3];
      w1[c] = Wdw[(c0 + c) * 3 + 1];
      w2[c] = Wdw[(c0 + c) * 3 + 2];
      bb[c] = bdw[c0 + c];
    }
#pragma unroll
    for (int jr = 0; jr < 4; ++jr) {
      const int tt = rowg * 4 + jr;
      const int n = tt & 2047;
      const bf16_t* ip = in + (size_t)tt * 4096 + c0;
      const uint4 z4 = {0, 0, 0, 0};
      uint4 um = (n > 0) ? *(const uint4*)(ip - 4096) : z4;
      uint4 uc = *(const uint4*)(ip);
      uint4 up = (n < 2047) ? *(const uint4*)(ip + 4096) : z4;
      float fm[8], fc[8], fp[8];
      exp8(um.x, um.y, um.z, um.w, fm);
      exp8(uc.x, uc.y, uc.z, uc.w, fc);
      exp8(up.x, up.y, up.z, up.w, fp);
      union {
        bf16_t b[8];
        uint4 u;
      } pk;
#pragma unroll
      for (int c = 0; c < 8; ++c)
        pk.b[c] =
            (bf16_t)(bb[c] + fm[c] * w0[c] + fc[c] * w1[c] + fp[c] * w2[c]);
      *(uint4*)(out + (size_t)tt * 2048 + c0) = pk.u;
    }
  }
}

// ---------------------------------------------------------------------------
extern "C" void kernel_launch(void* const* d_in, const int* in_sizes, int n_in,
                              void* d_out, int out_size, void* d_ws,
                              size_t ws_size, hipStream_t stream) {
  (void)in_sizes; (void)n_in; (void)out_size; (void)ws_size;
  const float* x = (const float*)d_in[0];
  const float* Wqkv = (const float*)d_in[1];
  const float* bqkv = (const float*)d_in[2];
  const float* Wout = (const float*)d_in[3];
  const float* bout = (const float*)d_in[4];
  const float* pos = (const float*)d_in[5];
  const float* Wcp = (const float*)d_in[6];
  const float* bcp = (const float*)d_in[7];
  const float* Wpw = (const float*)d_in[8];
  const float* bpw = (const float*)d_in[9];
  const float* Wdw = (const float*)d_in[10];
  const float* bdw = (const float*)d_in[11];
  const float* Wtw = (const float*)d_in[12];
  const float* btw = (const float*)d_in[13];
  float* out = (float*)d_out;

  char* ws = (char*)d_ws;
  const size_t MB = 1024ull * 1024ull;
  bf16_t* x_bf = (bf16_t*)(ws + 0);              // 16 MB (dead after GEMM1)
  bf16_t* Wbig1 = (bf16_t*)(ws + 16 * MB);       // 8 MB: [Wqkv ; Wcomb]
  bf16_t* WcpT = (bf16_t*)(ws + 24 * MB);        // 2 MB
  bf16_t* Wpw_bf = (bf16_t*)(ws + 26 * MB);      // 2 MB
  bf16_t* Mid = (bf16_t*)(ws + 0);               // 32 MB (after GEMM1)
  bf16_t* Wbig2 = (bf16_t*)(ws + 32 * MB);       // 4 MB: [Wout|Wtw] K-concat
  float* bias1 = (float*)(ws + 36 * MB);         // 16 KB
  float* bias2 = (float*)(ws + 36 * MB + 65536); // 4 KB
  bf16_t* G1out = (bf16_t*)(ws + 37 * MB);       // 64 MB: 8192 x 4096

  prep2_k<<<15620, 256, 0, stream>>>(x, x_bf, Wqkv, Wbig1, Wpw, Wpw_bf, Wout,
                                     Wtw, Wbig2, bqkv, bias1, bout, btw, bias2,
                                     Wcp, WcpT, bcp, bpw);

  // W_comb = W_pw @ W_cp -> rows 3072..4095 of Wbig1
  gemm_bt<2, 2, bf16_t><<<dim3(16, 16), 256, 0, stream>>>(
      Wpw_bf, WcpT, nullptr, Wbig1 + (size_t)3072 * 1024, 1024, 1024, 1024);

  // GEMM1: x @ [Wqkv ; Wcomb]^T + [bqkv ; bcomb] -> 8192 x 4096
  // 256^2 merged-region counted-vmcnt kernel; grid (N/256, M/256) = (16, 32).
  gemm8p<<<dim3(16, 32), 512, 0, stream>>>(x_bf, Wbig1, bias1, G1out, 8192,
                                           4096, 1024);

  // attention (cols 0..3071) -> Mid cols 0..1023; dwconv -> Mid cols 1024..
  mid_k<<<3072, 256, 0, stream>>>(G1out, pos, Wdw, bdw, Mid);

  // GEMM2: [attn|dwc] @ [Wout|Wtw]^T + (bout+btw) -> out (128x128 tiles)
  gemm_bt<4, 4, float><<<dim3(64, 8), 256, 0, stream>>>(Mid, Wbig2, bias2,
                                                        out, 8192, 1024, 2048);
}

// Round 4
// 265.890 us; speedup vs baseline: 1.0425x; 1.0425x over previous
//
#include <hip/hip_runtime.h>
#include <hip/hip_bf16.h>
#include <stdint.h>

// B=4, N=2048, C=1024, H=16, HD=64; 8192 token rows.
typedef __bf16 bf16_t;
typedef __attribute__((ext_vector_type(8))) __bf16 bf16x8;
typedef __attribute__((ext_vector_type(4))) __bf16 bf16x4;
typedef __attribute__((ext_vector_type(4))) float floatx4;
typedef __attribute__((ext_vector_type(4))) _Float16 half4_t;

#define GLDS16(g, l)                                                          \
  __builtin_amdgcn_global_load_lds(                                           \
      (const __attribute__((address_space(1))) void*)(g),                     \
      (__attribute__((address_space(3))) void*)(l), 16, 0, 0)

#define BAR8 asm volatile("s_barrier" ::: "memory")
#define VMCNT(n) asm volatile("s_waitcnt vmcnt(" #n ")" ::: "memory")

// ---------------------------------------------------------------------------
// Legacy 128x128 / 64x64 tile GEMM (m97 structure). Used for the small
// W_comb GEMM only.
// ---------------------------------------------------------------------------
template <int IT, int JT, typename OT>
__global__ __launch_bounds__(256) void gemm_bt(
    const bf16_t* __restrict__ A, const bf16_t* __restrict__ B,
    const float* __restrict__ bias, OT* __restrict__ C, int M, int N, int K) {
  constexpr int AROWS = 32 * IT;
  constexpr int BROWS = 32 * JT;
  constexpr int COLS = BROWS;
  constexpr int STAGE = (AROWS + BROWS) * 64;
  constexpr int EPI = (sizeof(OT) == 2) ? AROWS * COLS : 0;
  constexpr int SME = STAGE > EPI ? STAGE : EPI;
  __shared__ bf16_t sm[SME];
  bf16_t* As = sm;
  bf16_t* Bs = sm + AROWS * 64;

  const int tid = threadIdx.x;
  const int wave = tid >> 6;
  const int lane = tid & 63;
  const int quad = lane >> 4;
  const int l16 = lane & 15;
  const int m0 = blockIdx.x * AROWS;
  const int n0 = blockIdx.y * BROWS;
  const int wm = (wave >> 1) * (IT * 16);
  const int wn = (wave & 1) * (JT * 16);

  const int ra = wave * (8 * IT) + (lane >> 3);
  const int ga = ((lane & 7) ^ (ra & 7)) * 8;
  const int rb = wave * (8 * JT) + (lane >> 3);
  const int gb = ((lane & 7) ^ (rb & 7)) * 8;
  const bf16_t* Ab = A + (size_t)(m0 + ra) * K + ga;
  const bf16_t* Bb = B + (size_t)(n0 + rb) * K + gb;
  const int p0 = (quad ^ (l16 & 7)) * 8;

  floatx4 acc[IT][JT];
  const floatx4 zf = {0.f, 0.f, 0.f, 0.f};
#pragma unroll
  for (int i = 0; i < IT; ++i)
#pragma unroll
    for (int j = 0; j < JT; ++j) acc[i][j] = zf;

  for (int k0 = 0; k0 < K; k0 += 64) {
#pragma unroll
    for (int t = 0; t < IT; ++t)
      GLDS16(Ab + (size_t)(t * 8) * K + k0, As + (wave * (64 * IT) + t * 64) * 8);
#pragma unroll
    for (int t = 0; t < JT; ++t)
      GLDS16(Bb + (size_t)(t * 8) * K + k0, Bs + (wave * (64 * JT) + t * 64) * 8);
    __syncthreads();
#pragma unroll
    for (int ks = 0; ks < 2; ++ks) {
      const int ko = p0 ^ (ks * 32);
      bf16x8 af[IT], bfr[JT];
#pragma unroll
      for (int i = 0; i < IT; ++i)
        af[i] = *(const bf16x8*)(As + (wm + i * 16 + l16) * 64 + ko);
#pragma unroll
      for (int j = 0; j < JT; ++j)
        bfr[j] = *(const bf16x8*)(Bs + (wn + j * 16 + l16) * 64 + ko);
#pragma unroll
      for (int i = 0; i < IT; ++i)
#pragma unroll
        for (int j = 0; j < JT; ++j)
          acc[i][j] = __builtin_amdgcn_mfma_f32_16x16x32_bf16(
              bfr[j], af[i], acc[i][j], 0, 0, 0);
    }
    __syncthreads();
  }

  if constexpr (sizeof(OT) == 4) {
#pragma unroll
    for (int j = 0; j < JT; ++j) {
      const int colb = n0 + wn + j * 16 + quad * 4;
      floatx4 bv = zf;
      if (bias) bv = *(const floatx4*)(bias + colb);
#pragma unroll
      for (int i = 0; i < IT; ++i) {
        const int row = m0 + wm + i * 16 + l16;
        floatx4 v = acc[i][j] + bv;
        *(floatx4*)((float*)C + (size_t)row * N + colb) = v;
      }
    }
  } else {
    constexpr int SWZ = COLS / 32;
    constexpr int CPR = COLS / 8;
    constexpr int PASSES = (AROWS * CPR) / 256;
#pragma unroll
    for (int j = 0; j < JT; ++j) {
      const int colb = n0 + wn + j * 16 + quad * 4;
      floatx4 bv = zf;
      if (bias) bv = *(const floatx4*)(bias + colb);
      const int gcol = (wn + j * 16 + quad * 4) >> 2;
#pragma unroll
      for (int i = 0; i < IT; ++i) {
        const int rl = wm + i * 16 + l16;
        floatx4 v = acc[i][j] + bv;
        union {
          bf16_t b[4];
          uint2 u2;
        } pk;
        pk.b[0] = (bf16_t)v[0];
        pk.b[1] = (bf16_t)v[1];
        pk.b[2] = (bf16_t)v[2];
        pk.b[3] = (bf16_t)v[3];
        const int gsw = gcol ^ ((rl & 7) * SWZ);
        *(uint2*)(sm + rl * COLS + gsw * 4) = pk.u2;
      }
    }
    __syncthreads();
    bf16_t* Cb = (bf16_t*)C;
#pragma unroll
    for (int pass = 0; pass < PASSES; ++pass) {
      const int f = pass * 256 + tid;
      const int row = f / CPR;
      const int c16 = f % CPR;
      const int g0 = (2 * c16) ^ ((row & 7) * SWZ);
      uint4 v = *(const uint4*)(sm + row * COLS + g0 * 4);
      *(uint4*)(Cb + (size_t)(m0 + row) * N + n0 + c16 * 8) = v;
    }
  }
}

// ---------------------------------------------------------------------------
// 256x256 8-phase counted-vmcnt GEMM (round-1 body, verbatim: best measured
// GEMM1 = 72.6us / 946 TF). Round-3's merged-region variant regressed to
// 83us -> lockstep phases are NOT the limiter (m201 hits 62% with them);
// keep the 8-phase schedule.
// ---------------------------------------------------------------------------
__global__ __launch_bounds__(512, 2) void gemm8p(
    const bf16_t* __restrict__ A, const bf16_t* __restrict__ B,
    const float* __restrict__ bias, bf16_t* __restrict__ C, int M, int N,
    int K) {
  __shared__ bf16_t sm8[65536];  // 128 KiB; reused as 256x256 C-stage.
  bf16_t* As = sm8;              // [buf][kh][row 256][32] elems
  bf16_t* Bs = sm8 + 32768;

  const int tid = threadIdx.x;
  const int wave = tid >> 6, lane = tid & 63;
  const int l16 = lane & 15, quad = lane >> 4;
  const int wm = (wave >> 2) * 128, wn = (wave & 3) * 64;

  // XCD-aware swizzle (nwg % 8 == 0 for all our grids).
  const int lin = blockIdx.y * gridDim.x + blockIdx.x;
  const int nwg = gridDim.x * gridDim.y;
  const int chunk = nwg >> 3;
  const int swz = (lin & 7) * chunk + (lin >> 3);
  const int bm = swz / gridDim.x;
  const int bn = swz % gridDim.x;
  const int m0 = bm << 8, n0 = bn << 8;

  const int srow = wave * 32 + (lane >> 2);
  const int kswz = ((lane & 3) * 8) ^ ((lane >> 5) << 4);
  const bf16_t* Ag = A + (size_t)(m0 + srow) * K + kswz;
  const bf16_t* Bg = B + (size_t)(n0 + srow) * K + kswz;
  const int sdst = wave * 1024;
  const size_t a16k = (size_t)K << 4;

  const int koe = (quad * 8) ^ ((l16 & 8) << 1);
  const int aoff = (wm + l16) * 32 + koe;
  const int boff = (wn + l16) * 32 + koe;

  floatx4 acc[8][4];
  const floatx4 zf = {0.f, 0.f, 0.f, 0.f};
#pragma unroll
  for (int i = 0; i < 8; ++i)
#pragma unroll
    for (int j = 0; j < 4; ++j) acc[i][j] = zf;

  bf16x8 af[4], bfr[4];

#define STG_A(buf, kh, TOFF)                                     \
  do {                                                           \
    bf16_t* _d = As + (buf)*16384 + (kh)*8192 + sdst;            \
    GLDS16(Ag + (TOFF) + (kh)*32, _d);                           \
    GLDS16(Ag + a16k + (TOFF) + (kh)*32, _d + 512);              \
  } while (0)
#define STG_B(buf, kh, TOFF)                                     \
  do {                                                           \
    bf16_t* _d = Bs + (buf)*16384 + (kh)*8192 + sdst;            \
    GLDS16(Bg + (TOFF) + (kh)*32, _d);                           \
    GLDS16(Bg + a16k + (TOFF) + (kh)*32, _d + 512);              \
  } while (0)
#define LDA4(buf, ks, mb)                                        \
  do {                                                           \
    const bf16_t* _p = As + (buf)*16384 + (ks)*8192 + aoff + (mb)*512; \
    af[0] = *(const bf16x8*)(_p);                                \
    af[1] = *(const bf16x8*)(_p + 512);                          \
    af[2] = *(const bf16x8*)(_p + 1024);                         \
    af[3] = *(const bf16x8*)(_p + 1536);                         \
  } while (0)
#define LDB4(buf, ks)                                            \
  do {                                                           \
    const bf16_t* _p = Bs + (buf)*16384 + (ks)*8192 + boff;      \
    bfr[0] = *(const bf16x8*)(_p);                               \
    bfr[1] = *(const bf16x8*)(_p + 512);                         \
    bfr[2] = *(const bf16x8*)(_p + 1024);                        \
    bfr[3] = *(const bf16x8*)(_p + 1536);                        \
  } while (0)
#define MFMA16(mb)                                               \
  do {                                                           \
    __builtin_amdgcn_s_setprio(1);                               \
    _Pragma("unroll") for (int _i = 0; _i < 4; ++_i)             \
        _Pragma("unroll") for (int _j = 0; _j < 4; ++_j)         \
            acc[(mb) + _i][_j] =                                 \
                __builtin_amdgcn_mfma_f32_16x16x32_bf16(         \
                    bfr[_j], af[_i], acc[(mb) + _i][_j], 0, 0, 0); \
    __builtin_amdgcn_s_setprio(0);                               \
  } while (0)

  // Prologue: tile0 (4 half-tiles) + tile1 {Bk0,Ak0,Bk1}; wait tile0 landed.
  STG_A(0, 0, 0);
  STG_A(0, 1, 0);
  STG_B(0, 0, 0);
  STG_B(0, 1, 0);
  STG_B(1, 0, 64);
  STG_A(1, 0, 64);
  STG_B(1, 1, 64);
  VMCNT(6);
  BAR8;

  const int NT = K >> 6;
  for (int it = 0; it < NT / 2 - 1; ++it) {
    // phases 1-4: compute tile t (buf0); 5-8: tile t+1 (buf1)
    LDA4(0, 0, 0); LDB4(0, 0); STG_A(1, 1, 64);            BAR8; MFMA16(0); BAR8;
    LDA4(0, 0, 4);             STG_B(0, 0, 128);           BAR8; MFMA16(4); BAR8;
    LDA4(0, 1, 0); LDB4(0, 1); STG_A(0, 0, 128);           BAR8; MFMA16(0); BAR8;
    LDA4(0, 1, 4);             STG_B(0, 1, 128); VMCNT(6); BAR8; MFMA16(4); BAR8;
    LDA4(1, 0, 0); LDB4(1, 0); STG_A(0, 1, 128);           BAR8; MFMA16(0); BAR8;
    LDA4(1, 0, 4);             STG_B(1, 0, 192);           BAR8; MFMA16(4); BAR8;
    LDA4(1, 1, 0); LDB4(1, 1); STG_A(1, 0, 192);           BAR8; MFMA16(0); BAR8;
    LDA4(1, 1, 4);             STG_B(1, 1, 192); VMCNT(6); BAR8; MFMA16(4); BAR8;
    Ag += 128;
    Bg += 128;
  }
  // Tail iteration (tiles NT-2, NT-1): stage last half-tile, then drain.
  LDA4(0, 0, 0); LDB4(0, 0); STG_A(1, 1, 64); BAR8; MFMA16(0); BAR8;
  LDA4(0, 0, 4);                              BAR8; MFMA16(4); BAR8;
  LDA4(0, 1, 0); LDB4(0, 1);                  BAR8; MFMA16(0); BAR8;
  LDA4(0, 1, 4);             VMCNT(0);        BAR8; MFMA16(4); BAR8;
  LDA4(1, 0, 0); LDB4(1, 0);                  BAR8; MFMA16(0); BAR8;
  LDA4(1, 0, 4);                              BAR8; MFMA16(4); BAR8;
  LDA4(1, 1, 0); LDB4(1, 1);                  BAR8; MFMA16(0); BAR8;
  LDA4(1, 1, 4);                              BAR8; MFMA16(4); BAR8;

  // ---- bf16 epilogue: acc -> LDS (XOR-swizzled 8B granules) -> 16B stores.
  const int crow_b = wm + l16;
#pragma unroll
  for (int nj = 0; nj < 4; ++nj) {
    const int colb = wn + nj * 16 + quad * 4;
    floatx4 bv = zf;
    if (bias) bv = *(const floatx4*)(bias + n0 + colb);
#pragma unroll
    for (int mi = 0; mi < 8; ++mi) {
      const int row = crow_b + mi * 16;
      floatx4 v = acc[mi][nj] + bv;
      union {
        bf16_t b[4];
        uint2 u2;
      } pk;
      pk.b[0] = (bf16_t)v[0];
      pk.b[1] = (bf16_t)v[1];
      pk.b[2] = (bf16_t)v[2];
      pk.b[3] = (bf16_t)v[3];
      const int cb = (colb * 2) ^ ((row & 31) << 4);
      *(uint2*)((char*)sm8 + row * 512 + cb) = pk.u2;
    }
  }
  __syncthreads();
#pragma unroll
  for (int pass = 0; pass < 16; ++pass) {
    const int flat = pass * 8192 + tid * 16;
    const int row = flat >> 9;
    const int cb = flat & 511;
    const int cbs = cb ^ ((row & 31) << 4);
    uint4 v = *(const uint4*)((char*)sm8 + row * 512 + cbs);
    *(uint4*)((char*)C + ((size_t)(m0 + row) * N + n0) * 2 + cb) = v;
  }
#undef STG_A
#undef STG_B
#undef LDA4
#undef LDB4
#undef MFMA16
}

// ---------------------------------------------------------------------------
// 128x256-tile counted-vmcnt GEMM for GEMM2 (M=8192, N=1024, K=2048, fp32
// out). Grid (4,64) = 256 blocks = exactly 1 block/CU, single pass.
// 8 waves (2Mx4N), per-wave 64x64 (acc[4][4]). LDS 96 KiB:
// A [2buf][2kh][128][32] (32K) + B [2buf][2kh][256][32] (64K).
// Per tile: 6 GLDS16/thread (A-half=1, B-half=2); schedule stages 3/phase,
// VMCNT(3) at phases 2 & 4:
//   ph2's VMCNT(3) forces tile t+1 fully landed before ph3 reads buf1;
//   ph4's VMCNT(3) forces tile t+2 landed before next-iter ph1 reads buf0.
// Stage-target hazards: each region staged exactly one barrier after its
// last read (buf1-kh1@ph1, buf0-kh0@ph2, buf0-kh1@ph3, buf1-kh0@ph4).
// ---------------------------------------------------------------------------
__global__ __launch_bounds__(512, 2) void gemm8p2(
    const bf16_t* __restrict__ A, const bf16_t* __restrict__ B,
    const float* __restrict__ bias, float* __restrict__ C, int M, int N,
    int K) {
  __shared__ bf16_t sm2[49152];  // 96 KiB
  bf16_t* As = sm2;              // [buf][kh][128][32]
  bf16_t* Bs = sm2 + 16384;      // [buf][kh][256][32]

  const int tid = threadIdx.x;
  const int wave = tid >> 6, lane = tid & 63;
  const int l16 = lane & 15, quad = lane >> 4;
  const int wm = (wave >> 2) * 64, wn = (wave & 3) * 64;
  const int m0 = blockIdx.y << 7, n0 = blockIdx.x << 8;

  // Staging rows: A: wave*16 + lane/4 (128 rows, 1 GLDS16);
  //               B: wave*32 + lane/4 (+16) (256 rows, 2 GLDS16).
  // Global k-col pre-swizzled: row-bit3 (=lane>>5 for both layouts) XORs the
  // 16-elem k-granule -> linear GLDS write realizes the st_16x32 swizzle.
  const int srA = wave * 16 + (lane >> 2);
  const int srB = wave * 32 + (lane >> 2);
  const int kswz = ((lane & 3) * 8) ^ ((lane >> 5) << 4);
  const bf16_t* Ag = A + (size_t)(m0 + srA) * K + kswz;
  const bf16_t* Bg = B + (size_t)(n0 + srB) * K + kswz;
  const size_t b16k = (size_t)K << 4;  // 16 global rows of B

  const int koe = (quad * 8) ^ ((l16 & 8) << 1);
  const int aoff = (wm + l16) * 32 + koe;
  const int boff = (wn + l16) * 32 + koe;

  floatx4 acc[4][4];
  const floatx4 zf = {0.f, 0.f, 0.f, 0.f};
#pragma unroll
  for (int i = 0; i < 4; ++i)
#pragma unroll
    for (int j = 0; j < 4; ++j) acc[i][j] = zf;

  bf16x8 af[4], bfr[4];

#define SA2(buf, kh, TOFF)                                                 \
  GLDS16(Ag + (TOFF) + (kh)*32, As + (buf)*8192 + (kh)*4096 + wave * 512)
#define SB2(buf, kh, TOFF)                                                 \
  do {                                                                     \
    bf16_t* _d = Bs + (buf)*16384 + (kh)*8192 + wave * 1024;               \
    GLDS16(Bg + (TOFF) + (kh)*32, _d);                                     \
    GLDS16(Bg + b16k + (TOFF) + (kh)*32, _d + 512);                        \
  } while (0)
#define LD2(buf, kh)                                                       \
  do {                                                                     \
    const bf16_t* _pa = As + (buf)*8192 + (kh)*4096 + aoff;                \
    const bf16_t* _pb = Bs + (buf)*16384 + (kh)*8192 + boff;               \
    _Pragma("unroll") for (int _i = 0; _i < 4; ++_i)                       \
        af[_i] = *(const bf16x8*)(_pa + _i * 512);                         \
    _Pragma("unroll") for (int _j = 0; _j < 4; ++_j)                       \
        bfr[_j] = *(const bf16x8*)(_pb + _j * 512);                        \
  } while (0)
#define MM2                                                                \
  do {                                                                     \
    __builtin_amdgcn_s_setprio(1);                                         \
    _Pragma("unroll") for (int _i = 0; _i < 4; ++_i)                       \
        _Pragma("unroll") for (int _j = 0; _j < 4; ++_j)                   \
            acc[_i][_j] = __builtin_amdgcn_mfma_f32_16x16x32_bf16(         \
                bfr[_j], af[_i], acc[_i][_j], 0, 0, 0);                    \
    __builtin_amdgcn_s_setprio(0);                                         \
  } while (0)

  // Prologue: tile0 full (6 GLDS) + tile1 kh0 (3); wait tile0 landed.
  SA2(0, 0, 0);
  SB2(0, 0, 0);
  SA2(0, 1, 0);
  SB2(0, 1, 0);
  SA2(1, 0, 64);
  SB2(1, 0, 64);
  VMCNT(3);
  BAR8;

  const int NT = K >> 6;  // 32 tiles
  for (int it = 0; it < NT / 2 - 1; ++it) {
    // ph1: compute buf0/kh0; stage t+1 kh1 (-> buf1-kh1, last read prev ph4)
    LD2(0, 0); SA2(1, 1, 64);  SB2(1, 1, 64);            BAR8; MM2; BAR8;
    // ph2: compute buf0/kh1; stage t+2 kh0 (-> buf0-kh0, last read ph1)
    LD2(0, 1); SA2(0, 0, 128); SB2(0, 0, 128); VMCNT(3); BAR8; MM2; BAR8;
    // ph3: compute buf1/kh0; stage t+2 kh1 (-> buf0-kh1, last read ph2)
    LD2(1, 0); SA2(0, 1, 128); SB2(0, 1, 128);           BAR8; MM2; BAR8;
    // ph4: compute buf1/kh1; stage t+3 kh0 (-> buf1-kh0, last read ph3)
    LD2(1, 1); SA2(1, 0, 192); SB2(1, 0, 192); VMCNT(3); BAR8; MM2; BAR8;
    Ag += 128;
    Bg += 128;
  }
  // Tail: tiles NT-2 (buf0), NT-1 (buf1).
  LD2(0, 0); SA2(1, 1, 64); SB2(1, 1, 64); BAR8; MM2; BAR8;
  LD2(0, 1); VMCNT(0);                     BAR8; MM2; BAR8;
  LD2(1, 0);                               BAR8; MM2; BAR8;
  LD2(1, 1);                                     MM2;

  // fp32 epilogue: direct coalesced-ish 16B stores (same pattern as the
  // previous GEMM2 epilogue).
#pragma unroll
  for (int j = 0; j < 4; ++j) {
    const int colb = n0 + wn + j * 16 + quad * 4;
    floatx4 bv = zf;
    if (bias) bv = *(const floatx4*)(bias + colb);
#pragma unroll
    for (int i = 0; i < 4; ++i) {
      const int row = m0 + wm + i * 16 + l16;
      floatx4 v = acc[i][j] + bv;
      *(floatx4*)(C + (size_t)row * N + colb) = v;
    }
  }
#undef SA2
#undef SB2
#undef LD2
#undef MM2
}

// ---------------------------------------------------------------------------
// prep2: all fp32->bf16 converts, bias assembly, Wcp transpose, bcomb.
// ---------------------------------------------------------------------------
__global__ __launch_bounds__(256) void prep2_k(
    const float* __restrict__ x, bf16_t* __restrict__ x_bf,
    const float* __restrict__ Wqkv, bf16_t* __restrict__ Wbig1,
    const float* __restrict__ Wpw, bf16_t* __restrict__ Wpw_bf,
    const float* __restrict__ Wout, const float* __restrict__ Wtw,
    bf16_t* __restrict__ Wbig2, const float* __restrict__ bqkv,
    float* __restrict__ bias1, const float* __restrict__ bout,
    const float* __restrict__ btw, float* __restrict__ bias2,
    const float* __restrict__ Wcp, bf16_t* __restrict__ WcpT,
    const float* __restrict__ bcp, const float* __restrict__ bpw) {
  __shared__ float t[32][33];
  const int b = blockIdx.x, tid = threadIdx.x;
  auto cvt4 = [](const float* in, bf16_t* out, int i) {
    floatx4 v = ((const floatx4*)in)[i];
    bf16x4 o;
    o[0] = (bf16_t)v[0];
    o[1] = (bf16_t)v[1];
    o[2] = (bf16_t)v[2];
    o[3] = (bf16_t)v[3];
    ((bf16x4*)out)[i] = o;
  };
  if (b < 8192) {
    cvt4(x, x_bf, b * 256 + tid);
  } else if (b < 11264) {
    cvt4(Wqkv, Wbig1, (b - 8192) * 256 + tid);
  } else if (b < 12288) {
    cvt4(Wpw, Wpw_bf, (b - 11264) * 256 + tid);
  } else if (b < 14336) {
    const bool second = b >= 13312;
    int i = (b - (second ? 13312 : 12288)) * 256 + tid;
    floatx4 v = ((const floatx4*)(second ? Wtw : Wout))[i];
    bf16x4 o;
    o[0] = (bf16_t)v[0];
    o[1] = (bf16_t)v[1];
    o[2] = (bf16_t)v[2];
    o[3] = (bf16_t)v[3];
    int row = i >> 8, c4 = i & 255;
    *(bf16x4*)(Wbig2 + (size_t)row * 2048 + (second ? 1024 : 0) + c4 * 4) = o;
  } else if (b < 14339) {
    int i = (b - 14336) * 256 + tid;
    if (i < 768) ((floatx4*)bias1)[i] = ((const floatx4*)bqkv)[i];
  } else if (b == 14339) {
    ((floatx4*)bias2)[tid] =
        ((const floatx4*)bout)[tid] + ((const floatx4*)btw)[tid];
  } else if (b < 15364) {
    const int tb = b - 14340;
    const int bx = (tb & 31) * 32, by = (tb >> 5) * 32;
    const int tx = tid & 31, ty = tid >> 5;
#pragma unroll
    for (int iq = 0; iq < 4; ++iq)
      t[ty + iq * 8][tx] = Wcp[(size_t)(by + ty + iq * 8) * 1024 + bx + tx];
    __syncthreads();
#pragma unroll
    for (int iq = 0; iq < 4; ++iq)
      WcpT[(size_t)(bx + ty + iq * 8) * 1024 + by + tx] =
          (bf16_t)t[tx][ty + iq * 8];
  } else {
    const int row = (b - 15364) * 4 + (tid >> 6);
    const int l = tid & 63;
    const float* wr = Wpw + (size_t)row * 1024;
    float s = 0.f;
    for (int j = l; j < 1024; j += 64) s += wr[j] * bcp[j];
#pragma unroll
    for (int o = 32; o > 0; o >>= 1) s += __shfl_down(s, o);
    if (l == 0) bias1[3072 + row] = s + bpw[row];
  }
}

static __device__ inline void exp8(uint32_t w0, uint32_t w1, uint32_t w2,
                                   uint32_t w3, float* f) {
  f[0] = __uint_as_float(w0 << 16);
  f[1] = __uint_as_float(w0 & 0xffff0000u);
  f[2] = __uint_as_float(w1 << 16);
  f[3] = __uint_as_float(w1 & 0xffff0000u);
  f[4] = __uint_as_float(w2 << 16);
  f[5] = __uint_as_float(w2 & 0xffff0000u);
  f[6] = __uint_as_float(w3 << 16);
  f[7] = __uint_as_float(w3 & 0xffff0000u);
}

// ---------------------------------------------------------------------------
// mid: blocks [0,2048) = MFMA attention (one wave/token);
//      blocks [2048,3072) = depthwise conv k=3.
// ---------------------------------------------------------------------------
__global__ __launch_bounds__(256) void mid_k(const bf16_t* __restrict__ G1,
                                             const float* __restrict__ pos,
                                             const float* __restrict__ Wdw,
                                             const float* __restrict__ bdw,
                                             bf16_t* __restrict__ Mid) {
  __shared__ bf16_t ost[4][16 * 68];
  const int tid = threadIdx.x;
  if (blockIdx.x < 2048) {
    const int wave = tid >> 6, lane = tid & 63;
    const int p = blockIdx.x * 4 + wave;
    const int l16 = lane & 15, quad = lane >> 4;
    const bf16_t* row = G1 + (size_t)p * 4096;
    const bf16_t* qb = row + l16 * 192 + quad * 8;

    bf16x8 q0 = *(const bf16x8*)(qb);
    bf16x8 q1 = *(const bf16x8*)(qb + 32);
    bf16x8 k0 = *(const bf16x8*)(qb + 64);
    bf16x8 k1 = *(const bf16x8*)(qb + 96);
    floatx4 S = {0.f, 0.f, 0.f, 0.f};
    S = __builtin_amdgcn_mfma_f32_16x16x32_bf16(k0, q0, S, 0, 0, 0);
    S = __builtin_amdgcn_mfma_f32_16x16x32_bf16(k1, q1, S, 0, 0, 0);

    const floatx4 pb = *(const floatx4*)(pos + (size_t)(p & 2047) * 256 +
                                         l16 * 16 + quad * 4);
    float v[4];
#pragma unroll
    for (int r = 0; r < 4; ++r) v[r] = S[r] * 0.125f + pb[r];

    float m = fmaxf(fmaxf(v[0], v[1]), fmaxf(v[2], v[3]));
    m = fmaxf(m, __shfl_xor(m, 16));
    m = fmaxf(m, __shfl_xor(m, 32));
    float e[4], sum = 0.f;
#pragma unroll
    for (int r = 0; r < 4; ++r) {
      e[r] = __expf(v[r] - m);
      sum += e[r];
    }
    sum += __shfl_xor(sum, 16);
    sum += __shfl_xor(sum, 32);
    const float inv = 1.0f / sum;
    half4_t pa;
#pragma unroll
    for (int r = 0; r < 4; ++r) pa[r] = (_Float16)(e[r] * inv);

    const bf16_t* vb_base = row + 128 + l16;
    const floatx4 zf = {0.f, 0.f, 0.f, 0.f};
    floatx4 o[4];
#pragma unroll
    for (int t = 0; t < 4; ++t) {
      half4_t vb;
#pragma unroll
      for (int j = 0; j < 4; ++j)
        vb[j] = (_Float16)(float)vb_base[(quad * 4 + j) * 192 + t * 16];
      o[t] = __builtin_amdgcn_mfma_f32_16x16x16f16(pa, vb, zf, 0, 0, 0);
    }

    bf16_t* ow = ost[wave];
#pragma unroll
    for (int r = 0; r < 4; ++r)
#pragma unroll
      for (int t = 0; t < 4; ++t)
        ow[(quad * 4 + r) * 68 + t * 16 + l16] = (bf16_t)o[t][r];
    const int h2 = lane >> 2, m4 = lane & 3;
    const bf16_t* srcp = ow + h2 * 68 + m4 * 16;
    uint2 a0 = *(const uint2*)(srcp);
    uint2 a1 = *(const uint2*)(srcp + 4);
    uint2 a2 = *(const uint2*)(srcp + 8);
    uint2 a3 = *(const uint2*)(srcp + 12);
    uint4 s0 = {a0.x, a0.y, a1.x, a1.y};
    uint4 s1 = {a2.x, a2.y, a3.x, a3.y};
    uint4* dst = (uint4*)(Mid + (size_t)p * 2048 + h2 * 64 + m4 * 16);
    dst[0] = s0;
    dst[1] = s1;
  } else {
    const bf16_t* in = G1 + 3072;
    bf16_t* out = Mid + 1024;
    const int item = (blockIdx.x - 2048) * 256 + tid;
    const int cc = item & 127, rowg = item >> 7;
    const int c0 = cc * 8;
    float w0[8], w1[8], w2[8], bb[8];
#pragma unroll
    for (int c = 0; c < 8; ++c) {
      w0[c] = Wdw[(c0 + c) * 3];
      w1[c] = Wdw[(c0 + c) * 3 + 1];
      w2[c] = Wdw[(c0 + c) * 3 + 2];
      bb[c] = bdw[c0 + c];
    }
#pragma unroll
    for (int jr = 0; jr < 4; ++jr) {
      const int tt = rowg * 4 + jr;
      const int n = tt & 2047;
      const bf16_t* ip = in + (size_t)tt * 4096 + c0;
      const uint4 z4 = {0, 0, 0, 0};
      uint4 um = (n > 0) ? *(const uint4*)(ip - 4096) : z4;
      uint4 uc = *(const uint4*)(ip);
      uint4 up = (n < 2047) ? *(const uint4*)(ip + 4096) : z4;
      float fm[8], fc[8], fp[8];
      exp8(um.x, um.y, um.z, um.w, fm);
      exp8(uc.x, uc.y, uc.z, uc.w, fc);
      exp8(up.x, up.y, up.z, up.w, fp);
      union {
        bf16_t b[8];
        uint4 u;
      } pk;
#pragma unroll
      for (int c = 0; c < 8; ++c)
        pk.b[c] =
            (bf16_t)(bb[c] + fm[c] * w0[c] + fc[c] * w1[c] + fp[c] * w2[c]);
      *(uint4*)(out + (size_t)tt * 2048 + c0) = pk.u;
    }
  }
}

// ---------------------------------------------------------------------------
extern "C" void kernel_launch(void* const* d_in, const int* in_sizes, int n_in,
                              void* d_out, int out_size, void* d_ws,
                              size_t ws_size, hipStream_t stream) {
  (void)in_sizes; (void)n_in; (void)out_size; (void)ws_size;
  const float* x = (const float*)d_in[0];
  const float* Wqkv = (const float*)d_in[1];
  const float* bqkv = (const float*)d_in[2];
  const float* Wout = (const float*)d_in[3];
  const float* bout = (const float*)d_in[4];
  const float* pos = (const float*)d_in[5];
  const float* Wcp = (const float*)d_in[6];
  const float* bcp = (const float*)d_in[7];
  const float* Wpw = (const float*)d_in[8];
  const float* bpw = (const float*)d_in[9];
  const float* Wdw = (const float*)d_in[10];
  const float* bdw = (const float*)d_in[11];
  const float* Wtw = (const float*)d_in[12];
  const float* btw = (const float*)d_in[13];
  float* out = (float*)d_out;

  char* ws = (char*)d_ws;
  const size_t MB = 1024ull * 1024ull;
  bf16_t* x_bf = (bf16_t*)(ws + 0);              // 16 MB (dead after GEMM1)
  bf16_t* Wbig1 = (bf16_t*)(ws + 16 * MB);       // 8 MB: [Wqkv ; Wcomb]
  bf16_t* WcpT = (bf16_t*)(ws + 24 * MB);        // 2 MB
  bf16_t* Wpw_bf = (bf16_t*)(ws + 26 * MB);      // 2 MB
  bf16_t* Mid = (bf16_t*)(ws + 0);               // 32 MB (after GEMM1)
  bf16_t* Wbig2 = (bf16_t*)(ws + 32 * MB);       // 4 MB: [Wout|Wtw] K-concat
  float* bias1 = (float*)(ws + 36 * MB);         // 16 KB
  float* bias2 = (float*)(ws + 36 * MB + 65536); // 4 KB
  bf16_t* G1out = (bf16_t*)(ws + 37 * MB);       // 64 MB: 8192 x 4096

  prep2_k<<<15620, 256, 0, stream>>>(x, x_bf, Wqkv, Wbig1, Wpw, Wpw_bf, Wout,
                                     Wtw, Wbig2, bqkv, bias1, bout, btw, bias2,
                                     Wcp, WcpT, bcp, bpw);

  // W_comb = W_pw @ W_cp -> rows 3072..4095 of Wbig1
  gemm_bt<2, 2, bf16_t><<<dim3(16, 16), 256, 0, stream>>>(
      Wpw_bf, WcpT, nullptr, Wbig1 + (size_t)3072 * 1024, 1024, 1024, 1024);

  // GEMM1: x @ [Wqkv ; Wcomb]^T + [bqkv ; bcomb] -> 8192 x 4096
  gemm8p<<<dim3(16, 32), 512, 0, stream>>>(x_bf, Wbig1, bias1, G1out, 8192,
                                           4096, 1024);

  // attention (cols 0..3071) -> Mid cols 0..1023; dwconv -> Mid cols 1024..
  mid_k<<<3072, 256, 0, stream>>>(G1out, pos, Wdw, bdw, Mid);

  // GEMM2: [attn|dwc] @ [Wout|Wtw]^T + (bout+btw) -> out
  // 128x256-tile counted-vmcnt kernel; grid (N/256, M/128) = (4, 64).
  gemm8p2<<<dim3(4, 64), 512, 0, stream>>>(Mid, Wbig2, bias2, out, 8192, 1024,
                                           2048);
}